// Round 4
// baseline (97.954 us; speedup 1.0000x reference)
//
#include <hip/hip_runtime.h>
#include <hip/hip_cooperative_groups.h>
#include <math.h>

namespace cg = cooperative_groups;

// N=16384, D=64, C=64.
// loss = 1 - (1/n_unique) * sum_c [ (||S_c||^2 - n_c) / (n_c (n_c - 1)) ]
// where S_c = sum of row-normalized feature rows of class c.
//
// Single cooperative dispatch, 3 phases via grid.sync():
//   0: zero global acc/cnt (ws is poisoned; must re-init every call)
//   1: per-block LDS class-accumulate (64 rows/block), atomic flush to acc
//   2: block 0 reduces the 64x64 accumulator to the scalar loss.

#define NCLS 64
#define DIM 64
#define NBLK 256
#define THREADS 256
#define ROWS_PER_BLOCK 64   // 16384 / 256

__global__ __launch_bounds__(THREADS) void cpl_all(
    const float* __restrict__ feat,   // [n, DIM]
    const int* __restrict__ pred,     // [n]
    float* __restrict__ acc,          // ws: [NCLS*DIM]
    float* __restrict__ cnt,          // ws: [NCLS]
    float* __restrict__ out,          // [1]
    int n)
{
    cg::grid_group grid = cg::this_grid();
    const int tid = threadIdx.x;
    const int gid = blockIdx.x * THREADS + tid;

    // ---- phase 0: zero the global accumulator (blocks 0..16 do the writes)
    if (gid < NCLS * DIM) acc[gid] = 0.0f;
    if (gid < NCLS)       cnt[gid] = 0.0f;
    grid.sync();

    // ---- phase 1: block-local accumulate, then device-atomic flush
    __shared__ float s_acc[NCLS * DIM];
    __shared__ float s_cnt[NCLS];
    for (int i = tid; i < NCLS * DIM; i += THREADS) s_acc[i] = 0.0f;
    if (tid < NCLS) s_cnt[tid] = 0.0f;
    __syncthreads();

    const int lane = tid & 63;
    const int wave = tid >> 6;                                  // 0..3
    const int rpw  = ROWS_PER_BLOCK / (THREADS / 64);           // 16
    const int row0 = blockIdx.x * ROWS_PER_BLOCK + wave * rpw;

    for (int r = row0; r < row0 + rpw; ++r) {
        if (r >= n) break;
        float x = feat[(size_t)r * DIM + lane];                 // coalesced
        float s = x * x;
        #pragma unroll
        for (int off = 32; off; off >>= 1) s += __shfl_xor(s, off, 64);
        float v = x / sqrtf(s);                                 // normalized
        int c = pred[r];                                        // wave-uniform
        atomicAdd(&s_acc[c * DIM + lane], v);                   // LDS atomic
        if (lane == 0) atomicAdd(&s_cnt[c], 1.0f);
    }
    __syncthreads();

    for (int i = tid; i < NCLS * DIM; i += THREADS) {
        float v = s_acc[i];
        if (v != 0.0f) atomicAdd(&acc[i], v);                   // device atomic
    }
    if (tid < NCLS) {
        float v = s_cnt[tid];
        if (v != 0.0f) atomicAdd(&cnt[tid], v);
    }
    __threadfence();
    grid.sync();

    // ---- phase 2: block 0 finishes (reads 16.25 KB, L2-hot)
    if (blockIdx.x == 0) {
        __shared__ float s_avg[NCLS];
        __shared__ float s_pres[NCLS];
        const int c = tid >> 2;          // 4 threads per class
        const int part = tid & 3;

        float s = 0.0f;
        #pragma unroll
        for (int k = 0; k < 16; ++k) {
            float v = acc[c * DIM + part * 16 + k];
            s += v * v;
        }
        s += __shfl_xor(s, 1, 64);
        s += __shfl_xor(s, 2, 64);
        if (part == 0) {
            float nc = cnt[c];
            s_avg[c]  = (nc > 1.5f) ? (s - nc) / (nc * (nc - 1.0f)) : 0.0f;
            s_pres[c] = (nc > 0.5f) ? 1.0f : 0.0f;
        }
        __syncthreads();
        if (tid < 64) {
            float a  = s_avg[tid];
            float pr = s_pres[tid];
            #pragma unroll
            for (int off = 32; off; off >>= 1) {
                a  += __shfl_xor(a, off, 64);
                pr += __shfl_xor(pr, off, 64);
            }
            if (tid == 0) out[0] = 1.0f - a / pr;
        }
    }
}

extern "C" void kernel_launch(void* const* d_in, const int* in_sizes, int n_in,
                              void* d_out, int out_size, void* d_ws, size_t ws_size,
                              hipStream_t stream) {
    const float* feat = (const float*)d_in[0];
    const int*   pred = (const int*)d_in[1];
    float* out = (float*)d_out;
    int n = in_sizes[1];                       // 16384

    float* acc = (float*)d_ws;                 // NCLS*DIM floats
    float* cnt = acc + NCLS * DIM;             // NCLS floats

    void* args[] = { (void*)&feat, (void*)&pred, (void*)&acc,
                     (void*)&cnt, (void*)&out, (void*)&n };
    hipLaunchCooperativeKernel((const void*)cpl_all, dim3(NBLK), dim3(THREADS),
                               args, 0, stream);
}